// Round 5
// baseline (214.237 us; speedup 1.0000x reference)
//
#include <hip/hip_runtime.h>
#include <stdint.h>

#define N 4096
#define NH 8
#define NO 16
#define NF 6

typedef _Float16 half8 __attribute__((ext_vector_type(8)));
typedef float floatx4 __attribute__((ext_vector_type(4)));

// ---------------- workspace layout (bytes) ----------------
#define OFF_WHF  0          // 8*4096*16 fp16 = 1 MB, B-fragment order [h][mtile][lane][j]
#define OFF_ES   2097152    // 8*4096 f32  [h][n]
#define OFF_ED   2228224    // 8*4096 f32  [h][n]
#define OFF_X2   2359296    // 4096*128 f32 [n][h*16+o]
#define OFF_WH2  4456448    // 4096 f32
#define OFF_ED2  4472832    // 4096 f32
#define OFF_BITS 4489216    // TRANSPOSED bitmask: u64 [64 words][4096 rows] = 2 MB

// ---- kernel 1: Wh = x@W per head -> fp16 B-frag layout; es/ed = Wh.a halves ----
__global__ __launch_bounds__(256) void k_wh(const float* __restrict__ x,
                                            const float* __restrict__ W,
                                            const float* __restrict__ a,
                                            _Float16* __restrict__ Whf,
                                            float* __restrict__ es,
                                            float* __restrict__ ed) {
    int tid = blockIdx.x * 256 + threadIdx.x;   // 32768 threads: (n,h)
    int n = tid >> 3, h = tid & 7;
    float xf[NF];
#pragma unroll
    for (int f = 0; f < NF; ++f) xf[f] = x[n * NF + f];
    float wh[NO];
#pragma unroll
    for (int o = 0; o < NO; ++o) {
        float s = 0.f;
#pragma unroll
        for (int f = 0; f < NF; ++f) s = fmaf(xf[f], W[(h * NF + f) * NO + o], s);
        wh[o] = s;
    }
    float s1 = 0.f, s2 = 0.f;
#pragma unroll
    for (int o = 0; o < NO; ++o) {
        s1 = fmaf(wh[o], a[h * 32 + o], s1);
        s2 = fmaf(wh[o], a[h * 32 + 16 + o], s2);
    }
    // B-fragment scatter: for m-tile of 32, lane = q*16+o holds B[k=q*8+j][o],
    // i.e. element Wh[m0+q*8+j][o].  n -> tile=n>>5, q=(n>>3)&3, j=n&7.
    int tile = n >> 5, q = (n >> 3) & 3, j = n & 7;
    _Float16* base = Whf + ((size_t)((h << 7) + tile) << 9) + j;
#pragma unroll
    for (int o = 0; o < NO; ++o) base[(size_t)(((q << 4) + o) << 3)] = (_Float16)wh[o];
    es[(h << 12) + n] = s1;
    ed[(h << 12) + n] = s2;
}

// ---- kernel 2: pack adjacency to TRANSPOSED bitmask [word][row] ----
// Latency fix: 16 INDEPENDENT loads batched into registers, then 16 ballots.
// 2048 blocks * 4 waves = wave per half-row; 32 waves/CU resident.
__global__ __launch_bounds__(256) void k_bits(const int* __restrict__ adj,
                                              unsigned long long* __restrict__ bits) {
    int lane = threadIdx.x & 63;
    int wv = threadIdx.x >> 6;
    int n = ((blockIdx.x >> 1) << 2) + wv;          // row
    int wbase = (blockIdx.x & 1) << 5;              // word half: 0 or 32
    const int* row = adj + (size_t)n * N + (wbase << 6) + lane;
#pragma unroll
    for (int g = 0; g < 2; ++g) {
        int v[16];
#pragma unroll
        for (int i = 0; i < 16; ++i) v[i] = row[(((g << 4) + i) << 6)];
        unsigned long long b[16];
#pragma unroll
        for (int i = 0; i < 16; ++i) b[i] = __ballot(v[i] != 0);
        if (lane == 0) {
#pragma unroll
            for (int i = 0; i < 16; ++i)
                bits[((size_t)(wbase + (g << 4) + i) << 12) + n] = b[i];
        }
    }
}

// ---- kernel 3: layer-1 attention via fp16 MFMA 16x16x32 ----
// grid = 8 heads * 64 row-groups (64 rows each); block = 1024 = 16 waves,
// wave wv covers m in [wv*256, wv*256+256) in 32-m steps (8 steps).
// 2 blocks/CU * 16 waves = 32 waves/CU = full occupancy (VGPR 56 <= 64).
// P computed per-lane directly in A-fragment layout A[m=lane&15][k=quad*8+j];
// C/D layout: col=lane&15(=o), row=quad*4+reg.
__global__ __launch_bounds__(1024, 8) void k_attn1(const _Float16* __restrict__ Whf,
                                                   const float* __restrict__ es,
                                                   const float* __restrict__ ed,
                                                   const uint32_t* __restrict__ bits,
                                                   float* __restrict__ x2) {
    int h = blockIdx.x >> 6;
    int rg = blockIdx.x & 63;
    int lane = threadIdx.x & 63;
    int wv = threadIdx.x >> 6;          // 0..15
    int l15 = lane & 15, q = lane >> 4, qb = q << 3;
    int rowb = rg << 6;

    __shared__ float red[64][17];       // [row][o 0..15, den]
    for (int i = threadIdx.x; i < 64 * 17; i += 1024) ((float*)red)[i] = 0.f;
    __syncthreads();

    float esn[4];
    int rowoff[4];
#pragma unroll
    for (int t = 0; t < 4; ++t) {
        esn[t] = es[(h << 12) + rowb + (t << 4) + l15];
        rowoff[t] = (rowb + (t << 4) + l15) << 1;     // u32 index into bitsT column
    }

    floatx4 acc[4];
#pragma unroll
    for (int t = 0; t < 4; ++t) { acc[t][0]=0.f; acc[t][1]=0.f; acc[t][2]=0.f; acc[t][3]=0.f; }
    float den[4] = {0.f, 0.f, 0.f, 0.f};

    const float* edh = ed + (h << 12);

    for (int step = 0; step < 8; ++step) {
        int m0 = (wv << 8) + (step << 5);
        // ed for this lane's 8 k's (two float4, 16-lane broadcast)
        const floatx4* edp = (const floatx4*)(edh + m0 + qb);
        floatx4 ea = edp[0], eb = edp[1];
        float edj[8] = {ea[0],ea[1],ea[2],ea[3],eb[0],eb[1],eb[2],eb[3]};
        // B fragment: coalesced 16B/lane
        half8 bfrag = *(const half8*)(Whf + ((size_t)((h << 7) + (m0 >> 5)) << 9) + (lane << 3));
        // bitsT u32 word base for this 32-m window
        int wbase = ((m0 >> 6) << 13) + ((m0 >> 5) & 1);
#pragma unroll
        for (int t = 0; t < 4; ++t) {
            uint32_t w = bits[wbase + rowoff[t]] >> qb;   // this lane's 8 mask bits
            float ev[8];
#pragma unroll
            for (int j = 0; j < 8; ++j) {
                float s = esn[t] + edj[j];
                s = fmaxf(s, 0.2f * s);                   // leaky relu
                float e = __expf(s);
                e = (w & (1u << j)) ? e : 0.f;
                ev[j] = e;
                den[t] += e;
            }
            half8 afrag;
#pragma unroll
            for (int j = 0; j < 8; ++j) afrag[j] = (_Float16)ev[j];
            acc[t] = __builtin_amdgcn_mfma_f32_16x16x32_f16(afrag, bfrag, acc[t], 0, 0, 0);
        }
    }

    // combine partials (16 waves, m-split) via LDS atomics
#pragma unroll
    for (int t = 0; t < 4; ++t) {
        atomicAdd(&red[(t << 4) + l15][16], den[t]);
#pragma unroll
        for (int r = 0; r < 4; ++r)
            atomicAdd(&red[(t << 4) + (q << 2) + r][l15], acc[t][r]);
    }
    __syncthreads();

    {
        int r2 = threadIdx.x >> 4, c2 = threadIdx.x & 15;
        float v = red[r2][c2] / red[r2][16];
        v = v > 0.f ? v : expm1f(v);                     // jax.nn.elu
        x2[(size_t)(rowb + r2) * 128 + (h << 4) + c2] = v;
    }
}

// ---- kernel 4: Wh2 = x2 @ W_out (C=1), wave per row ----
__global__ __launch_bounds__(256) void k_wh2(const float* __restrict__ x2,
                                             const float* __restrict__ W_out,
                                             const float* __restrict__ a_out,
                                             float* __restrict__ Wh2,
                                             float* __restrict__ ed2) {
    int lane = threadIdx.x & 63;
    int n = (blockIdx.x << 2) + (threadIdx.x >> 6);
    const float2* xp = (const float2*)(x2 + (size_t)n * 128);
    const float2* wp = (const float2*)W_out;
    float2 xv = xp[lane], wv2 = wp[lane];
    float s = fmaf(xv.x, wv2.x, xv.y * wv2.y);
#pragma unroll
    for (int off = 32; off; off >>= 1) s += __shfl_xor(s, off);
    if (lane == 0) { Wh2[n] = s; ed2[n] = s * a_out[1]; }
}

// ---- kernel 5: layer-2 attention, block per row, 4 waves split m ----
__global__ __launch_bounds__(256) void k_attn2(const float* __restrict__ Wh2,
                                               const float* __restrict__ ed2,
                                               const float* __restrict__ a_out,
                                               const unsigned long long* __restrict__ bits,
                                               float* __restrict__ out) {
    int n = blockIdx.x;
    int lane = threadIdx.x & 63;
    int wv = threadIdx.x >> 6;
    float esn = Wh2[n] * a_out[0];
    float num = 0.f, den = 0.f;
#pragma unroll
    for (int it = 0; it < 16; ++it) {
        int w = (wv << 4) + it;
        int m = (w << 6) + lane;
        float w2 = Wh2[m];                               // coalesced
        float s = esn + ed2[m];                          // coalesced
        unsigned long long wb = bits[((size_t)w << 12) + n];  // uniform s_load
        s = fmaxf(s, 0.2f * s);
        float e = __expf(s);
        e = ((wb >> lane) & 1ull) ? e : 0.f;
        num = fmaf(e, w2, num);
        den += e;
    }
#pragma unroll
    for (int off = 32; off; off >>= 1) {
        num += __shfl_xor(num, off);
        den += __shfl_xor(den, off);
    }
    __shared__ float rn[4], rd[4];
    if (lane == 0) { rn[wv] = num; rd[wv] = den; }
    __syncthreads();
    if (threadIdx.x == 0) {
        float nn = rn[0] + rn[1] + rn[2] + rn[3];
        float dd = rd[0] + rd[1] + rd[2] + rd[3];
        float v = nn / dd;
        out[n] = v > 0.f ? v : expm1f(v);
    }
}

extern "C" void kernel_launch(void* const* d_in, const int* in_sizes, int n_in,
                              void* d_out, int out_size, void* d_ws, size_t ws_size,
                              hipStream_t stream) {
    const float* x     = (const float*)d_in[0];
    const int*   adj   = (const int*)d_in[1];
    const float* W     = (const float*)d_in[2];
    const float* a     = (const float*)d_in[3];
    const float* W_out = (const float*)d_in[4];
    const float* a_out = (const float*)d_in[5];
    float* out = (float*)d_out;

    char* ws = (char*)d_ws;
    _Float16* Whf = (_Float16*)(ws + OFF_WHF);
    float* es  = (float*)(ws + OFF_ES);
    float* ed  = (float*)(ws + OFF_ED);
    float* x2  = (float*)(ws + OFF_X2);
    float* Wh2 = (float*)(ws + OFF_WH2);
    float* ed2 = (float*)(ws + OFF_ED2);
    unsigned long long* bits = (unsigned long long*)(ws + OFF_BITS);

    hipLaunchKernelGGL(k_wh,    dim3(128),  dim3(256),  0, stream, x, W, a, Whf, es, ed);
    hipLaunchKernelGGL(k_bits,  dim3(2048), dim3(256),  0, stream, adj, bits);
    hipLaunchKernelGGL(k_attn1, dim3(512),  dim3(1024), 0, stream, Whf, es, ed,
                       (const uint32_t*)bits, x2);
    hipLaunchKernelGGL(k_wh2,   dim3(1024), dim3(256),  0, stream, x2, W_out, a_out, Wh2, ed2);
    hipLaunchKernelGGL(k_attn2, dim3(4096), dim3(256),  0, stream, Wh2, ed2, a_out,
                       bits, out);
}

// Round 6
// 197.353 us; speedup vs baseline: 1.0855x; 1.0855x over previous
//
#include <hip/hip_runtime.h>
#include <stdint.h>

#define N 4096
#define NH 8
#define NO 16
#define NF 6

typedef _Float16 half8 __attribute__((ext_vector_type(8)));
typedef float floatx4 __attribute__((ext_vector_type(4)));

// ---------------- workspace layout (bytes) ----------------
#define OFF_WHF  0          // 8*4096*16 fp16 = 1 MB, B-fragment order [h][mtile][lane][j]
#define OFF_ES   2097152    // 8*4096 f32  [h][n]
#define OFF_ED   2228224    // 8*4096 f32  [h][n]
#define OFF_X2   2359296    // 4096*128 f32 [n][h*16+o]
#define OFF_WH2  4456448    // 4096 f32
#define OFF_ED2  4472832    // 4096 f32
#define OFF_BITS 4489216    // TRANSPOSED bitmask: u64 [64 words][4096 rows] = 2 MB

// ---- kernel 1: Wh = x@W per head -> fp16 B-frag layout; es/ed = Wh.a halves ----
__global__ __launch_bounds__(256) void k_wh(const float* __restrict__ x,
                                            const float* __restrict__ W,
                                            const float* __restrict__ a,
                                            _Float16* __restrict__ Whf,
                                            float* __restrict__ es,
                                            float* __restrict__ ed) {
    int tid = blockIdx.x * 256 + threadIdx.x;   // 32768 threads: (n,h)
    int n = tid >> 3, h = tid & 7;
    float xf[NF];
#pragma unroll
    for (int f = 0; f < NF; ++f) xf[f] = x[n * NF + f];
    float wh[NO];
#pragma unroll
    for (int o = 0; o < NO; ++o) {
        float s = 0.f;
#pragma unroll
        for (int f = 0; f < NF; ++f) s = fmaf(xf[f], W[(h * NF + f) * NO + o], s);
        wh[o] = s;
    }
    float s1 = 0.f, s2 = 0.f;
#pragma unroll
    for (int o = 0; o < NO; ++o) {
        s1 = fmaf(wh[o], a[h * 32 + o], s1);
        s2 = fmaf(wh[o], a[h * 32 + 16 + o], s2);
    }
    // B-fragment scatter: for m-tile of 32, lane = q*16+o holds B[k=q*8+j][o],
    // i.e. element Wh[m0+q*8+j][o].  n -> tile=n>>5, q=(n>>3)&3, j=n&7.
    int tile = n >> 5, q = (n >> 3) & 3, j = n & 7;
    _Float16* base = Whf + ((size_t)((h << 7) + tile) << 9) + j;
#pragma unroll
    for (int o = 0; o < NO; ++o) base[(size_t)(((q << 4) + o) << 3)] = (_Float16)wh[o];
    es[(h << 12) + n] = s1;
    ed[(h << 12) + n] = s2;
}

// ---- kernel 2: pack adjacency to TRANSPOSED bitmask [word][row] ----
// Block per row (4096 blocks); wave owns 16 words, all 16 loads batched
// into registers before the ballots -> 4 KB in flight per wave.
__global__ __launch_bounds__(256) void k_bits(const int* __restrict__ adj,
                                              unsigned long long* __restrict__ bits) {
    int lane = threadIdx.x & 63;
    int wv = threadIdx.x >> 6;
    int n = blockIdx.x;
    int wbase = wv << 4;                            // 16 words per wave
    const int* row = adj + (size_t)n * N + (wbase << 6) + lane;
    int v[16];
#pragma unroll
    for (int i = 0; i < 16; ++i) v[i] = row[i << 6];
    unsigned long long b[16];
#pragma unroll
    for (int i = 0; i < 16; ++i) b[i] = __ballot(v[i] != 0);
    if (lane == 0) {
#pragma unroll
        for (int i = 0; i < 16; ++i)
            bits[((size_t)(wbase + i) << 12) + n] = b[i];
    }
}

// ---- kernel 3: layer-1 attention via fp16 MFMA 16x16x32 ----
// grid = 8 heads * 64 row-groups (64 rows each); block = 1024 = 16 waves,
// wave wv covers m in [wv*256, wv*256+256) in 32-m steps (8 steps).
// launch_bounds min-waves=4 (VGPR cap 128): kernel needs ~56 VGPR, so HW
// still fits 8 waves/EU WITHOUT forcing spills (R5's (1024,8) spilled:
// WRITE_SIZE 2->38 MB, dur 57->92 us).
// P computed per-lane directly in A-fragment layout A[m=lane&15][k=quad*8+j];
// C/D layout: col=lane&15(=o), row=quad*4+reg.
__global__ __launch_bounds__(1024, 4) void k_attn1(const _Float16* __restrict__ Whf,
                                                   const float* __restrict__ es,
                                                   const float* __restrict__ ed,
                                                   const uint32_t* __restrict__ bits,
                                                   float* __restrict__ x2) {
    int h = blockIdx.x >> 6;
    int rg = blockIdx.x & 63;
    int lane = threadIdx.x & 63;
    int wv = threadIdx.x >> 6;          // 0..15
    int l15 = lane & 15, q = lane >> 4, qb = q << 3;
    int rowb = rg << 6;

    __shared__ float red[64][17];       // [row][o 0..15, den]
    for (int i = threadIdx.x; i < 64 * 17; i += 1024) ((float*)red)[i] = 0.f;
    __syncthreads();

    float esn[4];
    int rowoff[4];
#pragma unroll
    for (int t = 0; t < 4; ++t) {
        esn[t] = es[(h << 12) + rowb + (t << 4) + l15];
        rowoff[t] = (rowb + (t << 4) + l15) << 1;     // u32 index into bitsT column
    }

    floatx4 acc[4];
#pragma unroll
    for (int t = 0; t < 4; ++t) { acc[t][0]=0.f; acc[t][1]=0.f; acc[t][2]=0.f; acc[t][3]=0.f; }
    float den[4] = {0.f, 0.f, 0.f, 0.f};

    const float* edh = ed + (h << 12);

    for (int step = 0; step < 8; ++step) {
        int m0 = (wv << 8) + (step << 5);
        // ed for this lane's 8 k's (two float4, 16-lane broadcast)
        const floatx4* edp = (const floatx4*)(edh + m0 + qb);
        floatx4 ea = edp[0], eb = edp[1];
        float edj[8] = {ea[0],ea[1],ea[2],ea[3],eb[0],eb[1],eb[2],eb[3]};
        // B fragment: coalesced 16B/lane
        half8 bfrag = *(const half8*)(Whf + ((size_t)((h << 7) + (m0 >> 5)) << 9) + (lane << 3));
        // bitsT u32 word base for this 32-m window
        int wbase = ((m0 >> 6) << 13) + ((m0 >> 5) & 1);
#pragma unroll
        for (int t = 0; t < 4; ++t) {
            uint32_t w = bits[wbase + rowoff[t]] >> qb;   // this lane's 8 mask bits
            float ev[8];
#pragma unroll
            for (int j = 0; j < 8; ++j) {
                float s = esn[t] + edj[j];
                s = fmaxf(s, 0.2f * s);                   // leaky relu
                float e = __expf(s);
                e = (w & (1u << j)) ? e : 0.f;
                ev[j] = e;
                den[t] += e;
            }
            half8 afrag;
#pragma unroll
            for (int j = 0; j < 8; ++j) afrag[j] = (_Float16)ev[j];
            acc[t] = __builtin_amdgcn_mfma_f32_16x16x32_f16(afrag, bfrag, acc[t], 0, 0, 0);
        }
    }

    // combine partials (16 waves, m-split) via LDS atomics
#pragma unroll
    for (int t = 0; t < 4; ++t) {
        atomicAdd(&red[(t << 4) + l15][16], den[t]);
#pragma unroll
        for (int r = 0; r < 4; ++r)
            atomicAdd(&red[(t << 4) + (q << 2) + r][l15], acc[t][r]);
    }
    __syncthreads();

    {
        int r2 = threadIdx.x >> 4, c2 = threadIdx.x & 15;
        float v = red[r2][c2] / red[r2][16];
        v = v > 0.f ? v : expm1f(v);                     // jax.nn.elu
        x2[(size_t)(rowb + r2) * 128 + (h << 4) + c2] = v;
    }
}

// ---- kernel 4: Wh2 = x2 @ W_out (C=1), wave per row ----
__global__ __launch_bounds__(256) void k_wh2(const float* __restrict__ x2,
                                             const float* __restrict__ W_out,
                                             const float* __restrict__ a_out,
                                             float* __restrict__ Wh2,
                                             float* __restrict__ ed2) {
    int lane = threadIdx.x & 63;
    int n = (blockIdx.x << 2) + (threadIdx.x >> 6);
    const float2* xp = (const float2*)(x2 + (size_t)n * 128);
    const float2* wp = (const float2*)W_out;
    float2 xv = xp[lane], wv2 = wp[lane];
    float s = fmaf(xv.x, wv2.x, xv.y * wv2.y);
#pragma unroll
    for (int off = 32; off; off >>= 1) s += __shfl_xor(s, off);
    if (lane == 0) { Wh2[n] = s; ed2[n] = s * a_out[1]; }
}

// ---- kernel 5: layer-2 attention, block per row, 4 waves split m ----
__global__ __launch_bounds__(256) void k_attn2(const float* __restrict__ Wh2,
                                               const float* __restrict__ ed2,
                                               const float* __restrict__ a_out,
                                               const unsigned long long* __restrict__ bits,
                                               float* __restrict__ out) {
    int n = blockIdx.x;
    int lane = threadIdx.x & 63;
    int wv = threadIdx.x >> 6;
    float esn = Wh2[n] * a_out[0];
    float num = 0.f, den = 0.f;
#pragma unroll
    for (int it = 0; it < 16; ++it) {
        int w = (wv << 4) + it;
        int m = (w << 6) + lane;
        float w2 = Wh2[m];                               // coalesced
        float s = esn + ed2[m];                          // coalesced
        unsigned long long wb = bits[((size_t)w << 12) + n];  // uniform s_load
        s = fmaxf(s, 0.2f * s);
        float e = __expf(s);
        e = ((wb >> lane) & 1ull) ? e : 0.f;
        num = fmaf(e, w2, num);
        den += e;
    }
#pragma unroll
    for (int off = 32; off; off >>= 1) {
        num += __shfl_xor(num, off);
        den += __shfl_xor(den, off);
    }
    __shared__ float rn[4], rd[4];
    if (lane == 0) { rn[wv] = num; rd[wv] = den; }
    __syncthreads();
    if (threadIdx.x == 0) {
        float nn = rn[0] + rn[1] + rn[2] + rn[3];
        float dd = rd[0] + rd[1] + rd[2] + rd[3];
        float v = nn / dd;
        out[n] = v > 0.f ? v : expm1f(v);
    }
}

extern "C" void kernel_launch(void* const* d_in, const int* in_sizes, int n_in,
                              void* d_out, int out_size, void* d_ws, size_t ws_size,
                              hipStream_t stream) {
    const float* x     = (const float*)d_in[0];
    const int*   adj   = (const int*)d_in[1];
    const float* W     = (const float*)d_in[2];
    const float* a     = (const float*)d_in[3];
    const float* W_out = (const float*)d_in[4];
    const float* a_out = (const float*)d_in[5];
    float* out = (float*)d_out;

    char* ws = (char*)d_ws;
    _Float16* Whf = (_Float16*)(ws + OFF_WHF);
    float* es  = (float*)(ws + OFF_ES);
    float* ed  = (float*)(ws + OFF_ED);
    float* x2  = (float*)(ws + OFF_X2);
    float* Wh2 = (float*)(ws + OFF_WH2);
    float* ed2 = (float*)(ws + OFF_ED2);
    unsigned long long* bits = (unsigned long long*)(ws + OFF_BITS);

    hipLaunchKernelGGL(k_wh,    dim3(128),  dim3(256),  0, stream, x, W, a, Whf, es, ed);
    hipLaunchKernelGGL(k_bits,  dim3(4096), dim3(256),  0, stream, adj, bits);
    hipLaunchKernelGGL(k_attn1, dim3(512),  dim3(1024), 0, stream, Whf, es, ed,
                       (const uint32_t*)bits, x2);
    hipLaunchKernelGGL(k_wh2,   dim3(1024), dim3(256),  0, stream, x2, W_out, a_out, Wh2, ed2);
    hipLaunchKernelGGL(k_attn2, dim3(4096), dim3(256),  0, stream, Wh2, ed2, a_out,
                       bits, out);
}

// Round 7
// 179.680 us; speedup vs baseline: 1.1923x; 1.0984x over previous
//
#include <hip/hip_runtime.h>
#include <stdint.h>

#define N 4096
#define NF 6
#define NO 16

typedef _Float16 half8 __attribute__((ext_vector_type(8)));
typedef float floatx4 __attribute__((ext_vector_type(4)));

// ---------------- workspace layout (bytes) ----------------
#define OFF_WHF  0          // 8*4096*16 fp16 = 1 MB, B-fragment order [h][mtile][lane][j]
#define OFF_ES   1048576    // 8*4096 f32  raw es
#define OFF_EN   1179648    // exp(es)
#define OFF_EN2  1310720    // exp(0.2 es)
#define OFF_ED   1441792    // raw ed
#define OFF_F    1572864    // exp(ed)
#define OFF_F2   1703936    // exp(0.2 ed)
#define OFF_X2   1835008    // 4096*128 f32 = 2 MB
#define OFF_WH2  3932160    // 4096 f32
#define OFF_ED2  3948544    // 4096 f32
#define OFF_BITS 3964928    // TRANSPOSED bitmask u64 [64 words][4096 rows] = 2 MB

// ---- kernel 1: Wh = x@W per head -> fp16 B-frag; es/ed + their exp tables ----
__global__ __launch_bounds__(256) void k_wh(const float* __restrict__ x,
                                            const float* __restrict__ W,
                                            const float* __restrict__ a,
                                            _Float16* __restrict__ Whf,
                                            float* __restrict__ es,
                                            float* __restrict__ en,
                                            float* __restrict__ en2,
                                            float* __restrict__ ed,
                                            float* __restrict__ fq,
                                            float* __restrict__ fq2) {
    int tid = blockIdx.x * 256 + threadIdx.x;   // 32768 threads: (n,h)
    int n = tid >> 3, h = tid & 7;
    float xf[NF];
#pragma unroll
    for (int f = 0; f < NF; ++f) xf[f] = x[n * NF + f];
    float wh[NO];
#pragma unroll
    for (int o = 0; o < NO; ++o) {
        float s = 0.f;
#pragma unroll
        for (int f = 0; f < NF; ++f) s = fmaf(xf[f], W[(h * NF + f) * NO + o], s);
        wh[o] = s;
    }
    float s1 = 0.f, s2 = 0.f;
#pragma unroll
    for (int o = 0; o < NO; ++o) {
        s1 = fmaf(wh[o], a[h * 32 + o], s1);
        s2 = fmaf(wh[o], a[h * 32 + 16 + o], s2);
    }
    // B-fragment scatter: lane q*16+o of an m-tile holds B[k=q*8+j][o]
    int tile = n >> 5, q = (n >> 3) & 3, j = n & 7;
    _Float16* base = Whf + ((size_t)((h << 7) + tile) << 9) + j;
#pragma unroll
    for (int o = 0; o < NO; ++o) base[(size_t)(((q << 4) + o) << 3)] = (_Float16)wh[o];
    int idx = (h << 12) + n;
    es[idx]  = s1;
    en[idx]  = __expf(s1);
    en2[idx] = __expf(0.2f * s1);
    ed[idx]  = s2;
    fq[idx]  = __expf(s2);
    fq2[idx] = __expf(0.2f * s2);
}

// ---- kernel 2: pack adjacency to TRANSPOSED bitmask [word][row] ----
// Block per row; wave owns 16 words, 16 loads batched before ballots.
__global__ __launch_bounds__(256) void k_bits(const int* __restrict__ adj,
                                              unsigned long long* __restrict__ bits) {
    int lane = threadIdx.x & 63;
    int wv = threadIdx.x >> 6;
    int n = blockIdx.x;
    int wbase = wv << 4;
    const int* row = adj + (size_t)n * N + (wbase << 6) + lane;
    int v[16];
#pragma unroll
    for (int i = 0; i < 16; ++i) v[i] = row[i << 6];
    unsigned long long b[16];
#pragma unroll
    for (int i = 0; i < 16; ++i) b[i] = __ballot(v[i] != 0);
    if (lane == 0) {
#pragma unroll
        for (int i = 0; i < 16; ++i)
            bits[((size_t)(wbase + i) << 12) + n] = b[i];
    }
}

// ---- kernel 3: layer-1 attention, exp-free inner loop + fp16 MFMA ----
// e = exp(lrelu(es+ed)) = (s>=0) ? En*F : En2*F2  -- all precomputed tables.
// den via MFMA with B=ones (free pipe). grid = 8 heads * 128 groups of 32
// rows = 1024 blocks (4/CU); block = 256 = 4 waves, wave wv covers m in
// [wv*1024, ...) over 32 steps of 32 m's (t=2 row-tiles of 16).
// A-frag: A[m=lane&15][k=quad*8+j]; C/D: col=lane&15, row=quad*4+reg.
__global__ __launch_bounds__(256, 4) void k_attn1(const _Float16* __restrict__ Whf,
                                                  const float* __restrict__ es,
                                                  const float* __restrict__ en,
                                                  const float* __restrict__ en2,
                                                  const float* __restrict__ ed,
                                                  const float* __restrict__ fq,
                                                  const float* __restrict__ fq2,
                                                  const uint32_t* __restrict__ bits,
                                                  float* __restrict__ x2) {
    int h = blockIdx.x >> 7;
    int rg = blockIdx.x & 127;
    int lane = threadIdx.x & 63;
    int wv = threadIdx.x >> 6;          // 0..3
    int l15 = lane & 15, q = lane >> 4, qb = q << 3;
    int rowb = rg << 5;

    __shared__ float red[32][17];       // [row][o 0..15, den]
    for (int i = threadIdx.x; i < 32 * 17; i += 256) ((float*)red)[i] = 0.f;
    __syncthreads();

    float esn[2], Ena[2], Enb[2];
    int rowoff[2];
#pragma unroll
    for (int t = 0; t < 2; ++t) {
        int row = rowb + (t << 4) + l15;
        esn[t] = es[(h << 12) + row];
        Ena[t] = en[(h << 12) + row];
        Enb[t] = en2[(h << 12) + row];
        rowoff[t] = row << 1;           // u32 index into bitsT column
    }

    floatx4 acc[2], accd[2];
#pragma unroll
    for (int t = 0; t < 2; ++t)
#pragma unroll
        for (int r = 0; r < 4; ++r) { acc[t][r] = 0.f; accd[t][r] = 0.f; }

    half8 ones;
#pragma unroll
    for (int j = 0; j < 8; ++j) ones[j] = (_Float16)1.0f;

    const float* edh = ed  + (h << 12);
    const float* Fh  = fq  + (h << 12);
    const float* F2h = fq2 + (h << 12);

    for (int step = 0; step < 32; ++step) {
        int m0 = (wv << 10) + (step << 5);
        const floatx4* pe = (const floatx4*)(edh + m0 + qb);
        const floatx4* pf = (const floatx4*)(Fh  + m0 + qb);
        const floatx4* pg = (const floatx4*)(F2h + m0 + qb);
        floatx4 ea = pe[0], eb = pe[1];
        floatx4 fa = pf[0], fb = pf[1];
        floatx4 ga = pg[0], gb = pg[1];
        float edj[8] = {ea[0],ea[1],ea[2],ea[3],eb[0],eb[1],eb[2],eb[3]};
        float Fj [8] = {fa[0],fa[1],fa[2],fa[3],fb[0],fb[1],fb[2],fb[3]};
        float F2j[8] = {ga[0],ga[1],ga[2],ga[3],gb[0],gb[1],gb[2],gb[3]};
        half8 bfrag = *(const half8*)(Whf + ((size_t)((h << 7) + (m0 >> 5)) << 9) + (lane << 3));
        int wbase = ((m0 >> 6) << 13) + ((m0 >> 5) & 1);
#pragma unroll
        for (int t = 0; t < 2; ++t) {
            uint32_t w = bits[wbase + rowoff[t]] >> qb;   // lane's 8 mask bits
            half8 afrag;
#pragma unroll
            for (int j = 0; j < 8; ++j) {
                float s = esn[t] + edj[j];
                bool pos = (s >= 0.f);
                float ff = pos ? Fj[j]  : F2j[j];
                float gg = pos ? Ena[t] : Enb[t];
                float e = ff * gg;
                e = (w & (1u << j)) ? e : 0.f;
                afrag[j] = (_Float16)e;
            }
            acc[t]  = __builtin_amdgcn_mfma_f32_16x16x32_f16(afrag, bfrag, acc[t], 0, 0, 0);
            accd[t] = __builtin_amdgcn_mfma_f32_16x16x32_f16(afrag, ones,  accd[t], 0, 0, 0);
        }
    }

    // combine 4 wave partials via LDS atomics
#pragma unroll
    for (int t = 0; t < 2; ++t)
#pragma unroll
        for (int r = 0; r < 4; ++r)
            atomicAdd(&red[(t << 4) + (q << 2) + r][l15], acc[t][r]);
    if (l15 == 0) {
#pragma unroll
        for (int t = 0; t < 2; ++t)
#pragma unroll
            for (int r = 0; r < 4; ++r)
                atomicAdd(&red[(t << 4) + (q << 2) + r][16], accd[t][r]);
    }
    __syncthreads();

#pragma unroll
    for (int i = threadIdx.x; i < 512; i += 256) {
        int r2 = i >> 4, c2 = i & 15;
        float v = red[r2][c2] / red[r2][16];
        v = v > 0.f ? v : expm1f(v);                     // jax.nn.elu
        x2[(size_t)(rowb + r2) * 128 + (h << 4) + c2] = v;
    }
}

// ---- kernel 4: Wh2 = x2 @ W_out (C=1), wave per row ----
__global__ __launch_bounds__(256) void k_wh2(const float* __restrict__ x2,
                                             const float* __restrict__ W_out,
                                             const float* __restrict__ a_out,
                                             float* __restrict__ Wh2,
                                             float* __restrict__ ed2) {
    int lane = threadIdx.x & 63;
    int n = (blockIdx.x << 2) + (threadIdx.x >> 6);
    const float2* xp = (const float2*)(x2 + (size_t)n * 128);
    const float2* wp = (const float2*)W_out;
    float2 xv = xp[lane], wv2 = wp[lane];
    float s = fmaf(xv.x, wv2.x, xv.y * wv2.y);
#pragma unroll
    for (int off = 32; off; off >>= 1) s += __shfl_xor(s, off);
    if (lane == 0) { Wh2[n] = s; ed2[n] = s * a_out[1]; }
}

// ---- kernel 5: layer-2 attention, block per row, 4 waves split m ----
__global__ __launch_bounds__(256) void k_attn2(const float* __restrict__ Wh2,
                                               const float* __restrict__ ed2,
                                               const float* __restrict__ a_out,
                                               const unsigned long long* __restrict__ bits,
                                               float* __restrict__ out) {
    int n = blockIdx.x;
    int lane = threadIdx.x & 63;
    int wv = threadIdx.x >> 6;
    float esn = Wh2[n] * a_out[0];
    float num = 0.f, den = 0.f;
#pragma unroll
    for (int it = 0; it < 16; ++it) {
        int w = (wv << 4) + it;
        int m = (w << 6) + lane;
        float w2 = Wh2[m];
        float s = esn + ed2[m];
        unsigned long long wb = bits[((size_t)w << 12) + n];
        s = fmaxf(s, 0.2f * s);
        float e = __expf(s);
        e = ((wb >> lane) & 1ull) ? e : 0.f;
        num = fmaf(e, w2, num);
        den += e;
    }
#pragma unroll
    for (int off = 32; off; off >>= 1) {
        num += __shfl_xor(num, off);
        den += __shfl_xor(den, off);
    }
    __shared__ float rn[4], rd[4];
    if (lane == 0) { rn[wv] = num; rd[wv] = den; }
    __syncthreads();
    if (threadIdx.x == 0) {
        float nn = rn[0] + rn[1] + rn[2] + rn[3];
        float dd = rd[0] + rd[1] + rd[2] + rd[3];
        float v = nn / dd;
        out[n] = v > 0.f ? v : expm1f(v);
    }
}

extern "C" void kernel_launch(void* const* d_in, const int* in_sizes, int n_in,
                              void* d_out, int out_size, void* d_ws, size_t ws_size,
                              hipStream_t stream) {
    const float* x     = (const float*)d_in[0];
    const int*   adj   = (const int*)d_in[1];
    const float* W     = (const float*)d_in[2];
    const float* a     = (const float*)d_in[3];
    const float* W_out = (const float*)d_in[4];
    const float* a_out = (const float*)d_in[5];
    float* out = (float*)d_out;

    char* ws = (char*)d_ws;
    _Float16* Whf = (_Float16*)(ws + OFF_WHF);
    float* es  = (float*)(ws + OFF_ES);
    float* en  = (float*)(ws + OFF_EN);
    float* en2 = (float*)(ws + OFF_EN2);
    float* ed  = (float*)(ws + OFF_ED);
    float* fq  = (float*)(ws + OFF_F);
    float* fq2 = (float*)(ws + OFF_F2);
    float* x2  = (float*)(ws + OFF_X2);
    float* Wh2 = (float*)(ws + OFF_WH2);
    float* ed2 = (float*)(ws + OFF_ED2);
    unsigned long long* bits = (unsigned long long*)(ws + OFF_BITS);

    hipLaunchKernelGGL(k_wh,    dim3(128),  dim3(256), 0, stream,
                       x, W, a, Whf, es, en, en2, ed, fq, fq2);
    hipLaunchKernelGGL(k_bits,  dim3(4096), dim3(256), 0, stream, adj, bits);
    hipLaunchKernelGGL(k_attn1, dim3(1024), dim3(256), 0, stream,
                       Whf, es, en, en2, ed, fq, fq2, (const uint32_t*)bits, x2);
    hipLaunchKernelGGL(k_wh2,   dim3(1024), dim3(256), 0, stream, x2, W_out, a_out, Wh2, ed2);
    hipLaunchKernelGGL(k_attn2, dim3(4096), dim3(256), 0, stream, Wh2, ed2, a_out, bits, out);
}

// Round 8
// 176.666 us; speedup vs baseline: 1.2127x; 1.0171x over previous
//
#include <hip/hip_runtime.h>
#include <stdint.h>

#define N 4096
#define NF 6
#define NO 16

typedef _Float16 half8 __attribute__((ext_vector_type(8)));
typedef float floatx4 __attribute__((ext_vector_type(4)));

// ---------------- workspace layout (bytes) ----------------
#define OFF_WHF  0          // 8*4096*16 fp16 = 1 MB, B-fragment order [h][mtile][lane][j]
#define OFF_EN   1048576    // exp(es)      [h][n]
#define OFF_EN2  1179648    // exp(0.2 es)  [h][n]
#define OFF_F    1310720    // exp(ed)      [h][n]
#define OFF_F2   1441792    // exp(0.2 ed)  [h][n]
#define OFF_X2   1572864    // 4096*128 f32 = 2 MB
#define OFF_WH2  3670016    // 4096 f32
#define OFF_ED2  3686400    // 4096 f32
#define OFF_BITS 3702784    // TRANSPOSED bitmask u64 [64 words][4096 rows] = 2 MB

// ---- kernel 1: Wh = x@W per head -> fp16 B-frag; exp tables of es/ed ----
__global__ __launch_bounds__(256) void k_wh(const float* __restrict__ x,
                                            const float* __restrict__ W,
                                            const float* __restrict__ a,
                                            _Float16* __restrict__ Whf,
                                            float* __restrict__ en,
                                            float* __restrict__ en2,
                                            float* __restrict__ fq,
                                            float* __restrict__ fq2) {
    int tid = blockIdx.x * 256 + threadIdx.x;   // 32768 threads: (n,h)
    int n = tid >> 3, h = tid & 7;
    float xf[NF];
#pragma unroll
    for (int f = 0; f < NF; ++f) xf[f] = x[n * NF + f];
    float wh[NO];
#pragma unroll
    for (int o = 0; o < NO; ++o) {
        float s = 0.f;
#pragma unroll
        for (int f = 0; f < NF; ++f) s = fmaf(xf[f], W[(h * NF + f) * NO + o], s);
        wh[o] = s;
    }
    float s1 = 0.f, s2 = 0.f;
#pragma unroll
    for (int o = 0; o < NO; ++o) {
        s1 = fmaf(wh[o], a[h * 32 + o], s1);
        s2 = fmaf(wh[o], a[h * 32 + 16 + o], s2);
    }
    // B-fragment scatter: lane q*16+o of an m-tile holds B[k=q*8+j][o]
    int tile = n >> 5, q = (n >> 3) & 3, j = n & 7;
    _Float16* base = Whf + ((size_t)((h << 7) + tile) << 9) + j;
#pragma unroll
    for (int o = 0; o < NO; ++o) base[(size_t)(((q << 4) + o) << 3)] = (_Float16)wh[o];
    int idx = (h << 12) + n;
    en[idx]  = __expf(s1);
    en2[idx] = __expf(0.2f * s1);
    fq[idx]  = __expf(s2);
    fq2[idx] = __expf(0.2f * s2);
}

// ---- kernel 2: pack adjacency to TRANSPOSED bitmask [word][row] ----
// Block per row; wave owns 16 words, 16 loads batched before ballots.
__global__ __launch_bounds__(256) void k_bits(const int* __restrict__ adj,
                                              unsigned long long* __restrict__ bits) {
    int lane = threadIdx.x & 63;
    int wv = threadIdx.x >> 6;
    int n = blockIdx.x;
    int wbase = wv << 4;
    const int* row = adj + (size_t)n * N + (wbase << 6) + lane;
    int v[16];
#pragma unroll
    for (int i = 0; i < 16; ++i) v[i] = row[i << 6];
    unsigned long long b[16];
#pragma unroll
    for (int i = 0; i < 16; ++i) b[i] = __ballot(v[i] != 0);
    if (lane == 0) {
#pragma unroll
        for (int i = 0; i < 16; ++i)
            bits[((size_t)(wbase + i) << 12) + n] = b[i];
    }
}

// ---- kernel 3: layer-1 attention, max-of-products inner loop + fp16 MFMA ----
// exp(lrelu(es+ed)) = max(exp(es)exp(ed), exp(.2es)exp(.2ed)) by monotonicity
// -> per score: mul, mul, max, mask-select, cvt. No add/cmp/exp.
// grid = 8 heads * 256 groups of 16 rows = 2048 blocks (8/CU -> 32 waves/CU);
// block = 256 = 4 waves; wave wv covers m in [wv*1024,...) in 32 steps of 32.
// den via MFMA with B=ones. A-frag A[m=lane&15][k=quad*8+j]; C/D col=lane&15,
// row=quad*4+reg.
__global__ __launch_bounds__(256, 4) void k_attn1(const _Float16* __restrict__ Whf,
                                                  const float* __restrict__ en,
                                                  const float* __restrict__ en2,
                                                  const float* __restrict__ fq,
                                                  const float* __restrict__ fq2,
                                                  const uint32_t* __restrict__ bits,
                                                  float* __restrict__ x2) {
    int h = blockIdx.x >> 8;
    int rg = blockIdx.x & 255;
    int lane = threadIdx.x & 63;
    int wv = threadIdx.x >> 6;          // 0..3
    int l15 = lane & 15, q = lane >> 4, qb = q << 3;
    int rowb = rg << 4;

    __shared__ float red[16][17];       // [row][o 0..15, den]
    for (int i = threadIdx.x; i < 16 * 17; i += 256) ((float*)red)[i] = 0.f;
    __syncthreads();

    int row = rowb + l15;
    float Ena = en [(h << 12) + row];
    float Enb = en2[(h << 12) + row];
    int rowoff = row << 1;              // u32 index into bitsT column

    floatx4 acc, accd;
#pragma unroll
    for (int r = 0; r < 4; ++r) { acc[r] = 0.f; accd[r] = 0.f; }

    half8 ones;
#pragma unroll
    for (int j = 0; j < 8; ++j) ones[j] = (_Float16)1.0f;

    const float* Fh  = fq  + (h << 12);
    const float* F2h = fq2 + (h << 12);

    for (int step = 0; step < 32; ++step) {
        int m0 = (wv << 10) + (step << 5);
        const floatx4* pf = (const floatx4*)(Fh  + m0 + qb);
        const floatx4* pg = (const floatx4*)(F2h + m0 + qb);
        floatx4 fa = pf[0], fb = pf[1];
        floatx4 ga = pg[0], gb = pg[1];
        float Fj [8] = {fa[0],fa[1],fa[2],fa[3],fb[0],fb[1],fb[2],fb[3]};
        float F2j[8] = {ga[0],ga[1],ga[2],ga[3],gb[0],gb[1],gb[2],gb[3]};
        half8 bfrag = *(const half8*)(Whf + ((size_t)((h << 7) + (m0 >> 5)) << 9) + (lane << 3));
        uint32_t w = bits[((m0 >> 6) << 13) + ((m0 >> 5) & 1) + rowoff] >> qb;
        half8 afrag;
#pragma unroll
        for (int j = 0; j < 8; ++j) {
            float e = fmaxf(Ena * Fj[j], Enb * F2j[j]);
            e = (w & (1u << j)) ? e : 0.f;
            afrag[j] = (_Float16)e;
        }
        acc  = __builtin_amdgcn_mfma_f32_16x16x32_f16(afrag, bfrag, acc,  0, 0, 0);
        accd = __builtin_amdgcn_mfma_f32_16x16x32_f16(afrag, ones,  accd, 0, 0, 0);
    }

    // combine 4 wave partials via LDS atomics
#pragma unroll
    for (int r = 0; r < 4; ++r)
        atomicAdd(&red[(q << 2) + r][l15], acc[r]);
    if (l15 == 0) {
#pragma unroll
        for (int r = 0; r < 4; ++r)
            atomicAdd(&red[(q << 2) + r][16], accd[r]);
    }
    __syncthreads();

    {
        int r2 = threadIdx.x >> 4, c2 = threadIdx.x & 15;
        float v = red[r2][c2] / red[r2][16];
        v = v > 0.f ? v : expm1f(v);                     // jax.nn.elu
        x2[(size_t)(rowb + r2) * 128 + (h << 4) + c2] = v;
    }
}

// ---- kernel 4: Wh2 = x2 @ W_out (C=1), wave per row ----
__global__ __launch_bounds__(256) void k_wh2(const float* __restrict__ x2,
                                             const float* __restrict__ W_out,
                                             const float* __restrict__ a_out,
                                             float* __restrict__ Wh2,
                                             float* __restrict__ ed2) {
    int lane = threadIdx.x & 63;
    int n = (blockIdx.x << 2) + (threadIdx.x >> 6);
    const float2* xp = (const float2*)(x2 + (size_t)n * 128);
    const float2* wp = (const float2*)W_out;
    float2 xv = xp[lane], wv2 = wp[lane];
    float s = fmaf(xv.x, wv2.x, xv.y * wv2.y);
#pragma unroll
    for (int off = 32; off; off >>= 1) s += __shfl_xor(s, off);
    if (lane == 0) { Wh2[n] = s; ed2[n] = s * a_out[1]; }
}

// ---- kernel 5: layer-2 attention, block per row, 4 waves split m ----
__global__ __launch_bounds__(256) void k_attn2(const float* __restrict__ Wh2,
                                               const float* __restrict__ ed2,
                                               const float* __restrict__ a_out,
                                               const unsigned long long* __restrict__ bits,
                                               float* __restrict__ out) {
    int n = blockIdx.x;
    int lane = threadIdx.x & 63;
    int wv = threadIdx.x >> 6;
    float esn = Wh2[n] * a_out[0];
    float num = 0.f, den = 0.f;
#pragma unroll
    for (int it = 0; it < 16; ++it) {
        int w = (wv << 4) + it;
        int m = (w << 6) + lane;
        float w2 = Wh2[m];
        float s = esn + ed2[m];
        unsigned long long wb = bits[((size_t)w << 12) + n];
        s = fmaxf(s, 0.2f * s);
        float e = __expf(s);
        e = ((wb >> lane) & 1ull) ? e : 0.f;
        num = fmaf(e, w2, num);
        den += e;
    }
#pragma unroll
    for (int off = 32; off; off >>= 1) {
        num += __shfl_xor(num, off);
        den += __shfl_xor(den, off);
    }
    __shared__ float rn[4], rd[4];
    if (lane == 0) { rn[wv] = num; rd[wv] = den; }
    __syncthreads();
    if (threadIdx.x == 0) {
        float nn = rn[0] + rn[1] + rn[2] + rn[3];
        float dd = rd[0] + rd[1] + rd[2] + rd[3];
        float v = nn / dd;
        out[n] = v > 0.f ? v : expm1f(v);
    }
}

extern "C" void kernel_launch(void* const* d_in, const int* in_sizes, int n_in,
                              void* d_out, int out_size, void* d_ws, size_t ws_size,
                              hipStream_t stream) {
    const float* x     = (const float*)d_in[0];
    const int*   adj   = (const int*)d_in[1];
    const float* W     = (const float*)d_in[2];
    const float* a     = (const float*)d_in[3];
    const float* W_out = (const float*)d_in[4];
    const float* a_out = (const float*)d_in[5];
    float* out = (float*)d_out;

    char* ws = (char*)d_ws;
    _Float16* Whf = (_Float16*)(ws + OFF_WHF);
    float* en  = (float*)(ws + OFF_EN);
    float* en2 = (float*)(ws + OFF_EN2);
    float* fq  = (float*)(ws + OFF_F);
    float* fq2 = (float*)(ws + OFF_F2);
    float* x2  = (float*)(ws + OFF_X2);
    float* Wh2 = (float*)(ws + OFF_WH2);
    float* ed2 = (float*)(ws + OFF_ED2);
    unsigned long long* bits = (unsigned long long*)(ws + OFF_BITS);

    hipLaunchKernelGGL(k_wh,    dim3(128),  dim3(256), 0, stream,
                       x, W, a, Whf, en, en2, fq, fq2);
    hipLaunchKernelGGL(k_bits,  dim3(4096), dim3(256), 0, stream, adj, bits);
    hipLaunchKernelGGL(k_attn1, dim3(2048), dim3(256), 0, stream,
                       Whf, en, en2, fq, fq2, (const uint32_t*)bits, x2);
    hipLaunchKernelGGL(k_wh2,   dim3(1024), dim3(256), 0, stream, x2, W_out, a_out, Wh2, ed2);
    hipLaunchKernelGGL(k_attn2, dim3(4096), dim3(256), 0, stream, Wh2, ed2, a_out, bits, out);
}

// Round 9
// 166.190 us; speedup vs baseline: 1.2891x; 1.0630x over previous
//
#include <hip/hip_runtime.h>
#include <stdint.h>

#define N 4096
#define NF 6
#define NO 16

typedef _Float16 half8 __attribute__((ext_vector_type(8)));
typedef _Float16 half2t __attribute__((ext_vector_type(2)));
typedef float floatx4 __attribute__((ext_vector_type(4)));

// ---------------- workspace layout (bytes) ----------------
#define OFF_WHF  0          // 8*4096*16 fp16 = 1 MB, B-fragment order [h][mtile][lane][j]
#define OFF_EN   1048576    // exp(es)      f32 [h][n]  (row-side, loaded once per block)
#define OFF_EN2  1179648    // exp(0.2 es)  f32 [h][n]
#define OFF_FH   1310720    // exp(ed)      fp16 [h][n] 64 KB
#define OFF_F2H  1376256    // exp(0.2 ed)  fp16 [h][n] 64 KB
#define OFF_X2   1441792    // 4096*128 f32 = 2 MB
#define OFF_WH2  3538944    // 4096 f32
#define OFF_ED2  3555328    // 4096 f32
#define OFF_BITS 3571712    // TRANSPOSED bitmask u64 [64 words][4096 rows] = 2 MB

// ---- kernel 1: Wh = x@W per head -> fp16 B-frag; exp tables of es/ed ----
__global__ __launch_bounds__(256) void k_wh(const float* __restrict__ x,
                                            const float* __restrict__ W,
                                            const float* __restrict__ a,
                                            _Float16* __restrict__ Whf,
                                            float* __restrict__ en,
                                            float* __restrict__ en2,
                                            _Float16* __restrict__ fh,
                                            _Float16* __restrict__ f2h) {
    int tid = blockIdx.x * 256 + threadIdx.x;   // 32768 threads: (n,h)
    int n = tid >> 3, h = tid & 7;
    float xf[NF];
#pragma unroll
    for (int f = 0; f < NF; ++f) xf[f] = x[n * NF + f];
    float wh[NO];
#pragma unroll
    for (int o = 0; o < NO; ++o) {
        float s = 0.f;
#pragma unroll
        for (int f = 0; f < NF; ++f) s = fmaf(xf[f], W[(h * NF + f) * NO + o], s);
        wh[o] = s;
    }
    float s1 = 0.f, s2 = 0.f;
#pragma unroll
    for (int o = 0; o < NO; ++o) {
        s1 = fmaf(wh[o], a[h * 32 + o], s1);
        s2 = fmaf(wh[o], a[h * 32 + 16 + o], s2);
    }
    // B-fragment scatter: lane q*16+o of an m-tile holds B[k=q*8+j][o]
    int tile = n >> 5, q = (n >> 3) & 3, j = n & 7;
    _Float16* base = Whf + ((size_t)((h << 7) + tile) << 9) + j;
#pragma unroll
    for (int o = 0; o < NO; ++o) base[(size_t)(((q << 4) + o) << 3)] = (_Float16)wh[o];
    int idx = (h << 12) + n;
    en [idx] = __expf(s1);
    en2[idx] = __expf(0.2f * s1);
    fh [idx] = (_Float16)__expf(s2);
    f2h[idx] = (_Float16)__expf(0.2f * s2);
}

// ---- kernel 2: pack adjacency to TRANSPOSED bitmask [word][row] ----
__global__ __launch_bounds__(256) void k_bits(const int* __restrict__ adj,
                                              unsigned long long* __restrict__ bits) {
    int lane = threadIdx.x & 63;
    int wv = threadIdx.x >> 6;
    int n = blockIdx.x;
    int wbase = wv << 4;
    const int* row = adj + (size_t)n * N + (wbase << 6) + lane;
    int v[16];
#pragma unroll
    for (int i = 0; i < 16; ++i) v[i] = row[i << 6];
    unsigned long long b[16];
#pragma unroll
    for (int i = 0; i < 16; ++i) b[i] = __ballot(v[i] != 0);
    if (lane == 0) {
#pragma unroll
        for (int i = 0; i < 16; ++i)
            bits[((size_t)(wbase + i) << 12) + n] = b[i];
    }
}

// ---- kernel 3: layer-1 attention, packed-fp16 inner loop + MFMA ----
// e = max(exp(es)exp(ed), exp(.2es)exp(.2ed)) computed 2-at-a-time with
// v_pk_mul/v_pk_max; adjacency mask applied as bitwise AND with an LDS
// LUT mask (fp16 +0.0 == 0x0000), so masked e's are exact zeros and the
// pk results directly form the MFMA A-fragment (no cvt/pack chain).
// grid = 8 heads * 256 groups of 16 rows = 2048 blocks; block = 4 waves;
// wave wv covers m in [wv*1024,...) in 32 steps of 32.
// A-frag A[n=lane&15][k=q*8+j]; C/D col=lane&15, row=q*4+reg.
__global__ __launch_bounds__(256, 4) void k_attn1(const _Float16* __restrict__ Whf,
                                                  const float* __restrict__ en,
                                                  const float* __restrict__ en2,
                                                  const _Float16* __restrict__ fh,
                                                  const _Float16* __restrict__ f2h,
                                                  const uint32_t* __restrict__ bits,
                                                  float* __restrict__ x2) {
    int h = blockIdx.x >> 8;
    int rg = blockIdx.x & 255;
    int lane = threadIdx.x & 63;
    int wv = threadIdx.x >> 6;          // 0..3
    int l15 = lane & 15, q = lane >> 4, qb = q << 3;
    int rowb = rg << 4;

    __shared__ float red[16][17];       // [row][o 0..15, den]
    __shared__ uint64_t lut[16];        // nibble -> two u32 half-masks
    for (int i = threadIdx.x; i < 16 * 17; i += 256) ((float*)red)[i] = 0.f;
    if (threadIdx.x < 16) {
        uint32_t v = threadIdx.x;
        uint32_t lo = ((v & 1) ? 0x0000FFFFu : 0u) | ((v & 2) ? 0xFFFF0000u : 0u);
        uint32_t hi = ((v & 4) ? 0x0000FFFFu : 0u) | ((v & 8) ? 0xFFFF0000u : 0u);
        lut[v] = ((uint64_t)hi << 32) | lo;
    }
    __syncthreads();

    int row = rowb + l15;
    float EnaF = en [(h << 12) + row];
    float EnbF = en2[(h << 12) + row];
    _Float16 ha = (_Float16)EnaF, hb = (_Float16)EnbF;
    half2t ena2 = {ha, ha}, enb2 = {hb, hb};
    int rowoff = row << 1;              // u32 index into bitsT column

    floatx4 acc, accd;
#pragma unroll
    for (int r = 0; r < 4; ++r) { acc[r] = 0.f; accd[r] = 0.f; }

    half8 ones;
#pragma unroll
    for (int j = 0; j < 8; ++j) ones[j] = (_Float16)1.0f;

    const _Float16* Fh  = fh  + (h << 12);
    const _Float16* F2h = f2h + (h << 12);

    for (int step = 0; step < 32; ++step) {
        int m0 = (wv << 10) + (step << 5);
        union { half8 v; half2t h2[4]; uint32_t u[4]; } F, G, A;
        F.v = *(const half8*)(Fh  + m0 + qb);
        G.v = *(const half8*)(F2h + m0 + qb);
        half8 bfrag = *(const half8*)(Whf + ((size_t)((h << 7) + (m0 >> 5)) << 9) + (lane << 3));
        uint32_t w = bits[((m0 >> 6) << 13) + ((m0 >> 5) & 1) + rowoff] >> qb;
        uint64_t mlo = lut[w & 15];
        uint64_t mhi = lut[(w >> 4) & 15];
        uint32_t msk[4] = {(uint32_t)mlo, (uint32_t)(mlo >> 32),
                           (uint32_t)mhi, (uint32_t)(mhi >> 32)};
#pragma unroll
        for (int p = 0; p < 4; ++p) {
            half2t e = __builtin_elementwise_max(ena2 * F.h2[p], enb2 * G.h2[p]);
            A.u[p] = __builtin_bit_cast(uint32_t, e) & msk[p];
        }
        acc  = __builtin_amdgcn_mfma_f32_16x16x32_f16(A.v, bfrag, acc,  0, 0, 0);
        accd = __builtin_amdgcn_mfma_f32_16x16x32_f16(A.v, ones,  accd, 0, 0, 0);
    }

    // combine 4 wave partials via LDS atomics
#pragma unroll
    for (int r = 0; r < 4; ++r)
        atomicAdd(&red[(q << 2) + r][l15], acc[r]);
    if (l15 == 0) {
#pragma unroll
        for (int r = 0; r < 4; ++r)
            atomicAdd(&red[(q << 2) + r][16], accd[r]);
    }
    __syncthreads();

    {
        int r2 = threadIdx.x >> 4, c2 = threadIdx.x & 15;
        float v = red[r2][c2] / red[r2][16];
        v = v > 0.f ? v : expm1f(v);                     // jax.nn.elu
        x2[(size_t)(rowb + r2) * 128 + (h << 4) + c2] = v;
    }
}

// ---- kernel 4: Wh2 = x2 @ W_out (C=1), wave per row ----
__global__ __launch_bounds__(256) void k_wh2(const float* __restrict__ x2,
                                             const float* __restrict__ W_out,
                                             const float* __restrict__ a_out,
                                             float* __restrict__ Wh2,
                                             float* __restrict__ ed2) {
    int lane = threadIdx.x & 63;
    int n = (blockIdx.x << 2) + (threadIdx.x >> 6);
    const float2* xp = (const float2*)(x2 + (size_t)n * 128);
    const float2* wp = (const float2*)W_out;
    float2 xv = xp[lane], wv2 = wp[lane];
    float s = fmaf(xv.x, wv2.x, xv.y * wv2.y);
#pragma unroll
    for (int off = 32; off; off >>= 1) s += __shfl_xor(s, off);
    if (lane == 0) { Wh2[n] = s; ed2[n] = s * a_out[1]; }
}

// ---- kernel 5: layer-2 attention, block per row, 4 waves split m ----
__global__ __launch_bounds__(256) void k_attn2(const float* __restrict__ Wh2,
                                               const float* __restrict__ ed2,
                                               const float* __restrict__ a_out,
                                               const unsigned long long* __restrict__ bits,
                                               float* __restrict__ out) {
    int n = blockIdx.x;
    int lane = threadIdx.x & 63;
    int wv = threadIdx.x >> 6;
    float esn = Wh2[n] * a_out[0];
    float num = 0.f, den = 0.f;
#pragma unroll
    for (int it = 0; it < 16; ++it) {
        int w = (wv << 4) + it;
        int m = (w << 6) + lane;
        float w2 = Wh2[m];
        float s = esn + ed2[m];
        unsigned long long wb = bits[((size_t)w << 12) + n];
        s = fmaxf(s, 0.2f * s);
        float e = __expf(s);
        e = ((wb >> lane) & 1ull) ? e : 0.f;
        num = fmaf(e, w2, num);
        den += e;
    }
#pragma unroll
    for (int off = 32; off; off >>= 1) {
        num += __shfl_xor(num, off);
        den += __shfl_xor(den, off);
    }
    __shared__ float rn[4], rd[4];
    if (lane == 0) { rn[wv] = num; rd[wv] = den; }
    __syncthreads();
    if (threadIdx.x == 0) {
        float nn = rn[0] + rn[1] + rn[2] + rn[3];
        float dd = rd[0] + rd[1] + rd[2] + rd[3];
        float v = nn / dd;
        out[n] = v > 0.f ? v : expm1f(v);
    }
}

extern "C" void kernel_launch(void* const* d_in, const int* in_sizes, int n_in,
                              void* d_out, int out_size, void* d_ws, size_t ws_size,
                              hipStream_t stream) {
    const float* x     = (const float*)d_in[0];
    const int*   adj   = (const int*)d_in[1];
    const float* W     = (const float*)d_in[2];
    const float* a     = (const float*)d_in[3];
    const float* W_out = (const float*)d_in[4];
    const float* a_out = (const float*)d_in[5];
    float* out = (float*)d_out;

    char* ws = (char*)d_ws;
    _Float16* Whf = (_Float16*)(ws + OFF_WHF);
    float* en  = (float*)(ws + OFF_EN);
    float* en2 = (float*)(ws + OFF_EN2);
    _Float16* fhh  = (_Float16*)(ws + OFF_FH);
    _Float16* f2hh = (_Float16*)(ws + OFF_F2H);
    float* x2  = (float*)(ws + OFF_X2);
    float* Wh2 = (float*)(ws + OFF_WH2);
    float* ed2 = (float*)(ws + OFF_ED2);
    unsigned long long* bits = (unsigned long long*)(ws + OFF_BITS);

    hipLaunchKernelGGL(k_wh,    dim3(128),  dim3(256), 0, stream,
                       x, W, a, Whf, en, en2, fhh, f2hh);
    hipLaunchKernelGGL(k_bits,  dim3(4096), dim3(256), 0, stream, adj, bits);
    hipLaunchKernelGGL(k_attn1, dim3(2048), dim3(256), 0, stream,
                       Whf, en, en2, fhh, f2hh, (const uint32_t*)bits, x2);
    hipLaunchKernelGGL(k_wh2,   dim3(1024), dim3(256), 0, stream, x2, W_out, a_out, Wh2, ed2);
    hipLaunchKernelGGL(k_attn2, dim3(4096), dim3(256), 0, stream, Wh2, ed2, a_out, bits, out);
}

// Round 10
// 157.099 us; speedup vs baseline: 1.3637x; 1.0579x over previous
//
#include <hip/hip_runtime.h>
#include <stdint.h>

#define N 4096
#define NF 6
#define NO 16

typedef _Float16 half8 __attribute__((ext_vector_type(8)));
typedef _Float16 half2t __attribute__((ext_vector_type(2)));
typedef float floatx4 __attribute__((ext_vector_type(4)));

// ---------------- workspace layout (bytes) ----------------
#define OFF_WHF  0          // 8*4096*16 fp16 = 1 MB, B-fragment order [h][mtile][lane][j]
#define OFF_EN   1048576    // exp(es)      f32 [h][n]
#define OFF_EN2  1179648    // exp(0.2 es)  f32 [h][n]
#define OFF_FH   1310720    // exp(ed)      fp16 [h][n] 64 KB
#define OFF_F2H  1376256    // exp(0.2 ed)  fp16 [h][n] 64 KB
#define OFF_X2   1441792    // 4096*128 f32 = 2 MB
#define OFF_WH2  3538944    // 4096 f32
#define OFF_ED2  3555328    // 4096 f32
#define OFF_BITS 3571712    // TRANSPOSED bitmask u64 [64 words][4096 rows] = 2 MB

// ---- kernel 1: Wh = x@W per head -> fp16 B-frag; exp tables of es/ed ----
__global__ __launch_bounds__(256) void k_wh(const float* __restrict__ x,
                                            const float* __restrict__ W,
                                            const float* __restrict__ a,
                                            _Float16* __restrict__ Whf,
                                            float* __restrict__ en,
                                            float* __restrict__ en2,
                                            _Float16* __restrict__ fh,
                                            _Float16* __restrict__ f2h) {
    int tid = blockIdx.x * 256 + threadIdx.x;   // 32768 threads: (n,h)
    int n = tid >> 3, h = tid & 7;
    float xf[NF];
#pragma unroll
    for (int f = 0; f < NF; ++f) xf[f] = x[n * NF + f];
    float wh[NO];
#pragma unroll
    for (int o = 0; o < NO; ++o) {
        float s = 0.f;
#pragma unroll
        for (int f = 0; f < NF; ++f) s = fmaf(xf[f], W[(h * NF + f) * NO + o], s);
        wh[o] = s;
    }
    float s1 = 0.f, s2 = 0.f;
#pragma unroll
    for (int o = 0; o < NO; ++o) {
        s1 = fmaf(wh[o], a[h * 32 + o], s1);
        s2 = fmaf(wh[o], a[h * 32 + 16 + o], s2);
    }
    // B-fragment scatter: lane q*16+o of an m-tile holds B[k=q*8+j][o]
    int tile = n >> 5, q = (n >> 3) & 3, j = n & 7;
    _Float16* base = Whf + ((size_t)((h << 7) + tile) << 9) + j;
#pragma unroll
    for (int o = 0; o < NO; ++o) base[(size_t)(((q << 4) + o) << 3)] = (_Float16)wh[o];
    int idx = (h << 12) + n;
    en [idx] = __expf(s1);
    en2[idx] = __expf(0.2f * s1);
    fh [idx] = (_Float16)__expf(s2);
    f2h[idx] = (_Float16)__expf(0.2f * s2);
}

// ---- kernel 2: pack adjacency to TRANSPOSED bitmask [word][row] ----
__global__ __launch_bounds__(256) void k_bits(const int* __restrict__ adj,
                                              unsigned long long* __restrict__ bits) {
    int lane = threadIdx.x & 63;
    int wv = threadIdx.x >> 6;
    int n = blockIdx.x;
    int wbase = wv << 4;
    const int* row = adj + (size_t)n * N + (wbase << 6) + lane;
    int v[16];
#pragma unroll
    for (int i = 0; i < 16; ++i) v[i] = row[i << 6];
    unsigned long long b[16];
#pragma unroll
    for (int i = 0; i < 16; ++i) b[i] = __ballot(v[i] != 0);
    if (lane == 0) {
#pragma unroll
        for (int i = 0; i < 16; ++i)
            bits[((size_t)(wbase + i) << 12) + n] = b[i];
    }
}

// ---- kernel 3: layer-1 attention, packed-fp16 + MFMA, LDS-staged tables ----
// R9 was L1-pipe-bound: F/G quad-broadcast global loads pushed 16x redundant
// bytes through L1 (1 KB/inst for 64 B unique). R10 stages F/F2 in LDS once
// per block (16 KB coop copy), per-step reads become conflict-free
// ds_read_b128 quad-broadcasts on the otherwise-idle LDS pipe.
// e = max(exp(es)exp(ed), exp(.2es)exp(.2ed)); mask via AND with LDS LUT.
// grid = 8 heads * 256 groups of 16 rows = 2048 blocks; block = 4 waves;
// wave wv covers m in [wv*1024,...) in 32 steps of 32.
__global__ __launch_bounds__(256, 4) void k_attn1(const _Float16* __restrict__ Whf,
                                                  const float* __restrict__ en,
                                                  const float* __restrict__ en2,
                                                  const _Float16* __restrict__ fh,
                                                  const _Float16* __restrict__ f2h,
                                                  const uint32_t* __restrict__ bits,
                                                  float* __restrict__ x2) {
    int h = blockIdx.x >> 8;
    int rg = blockIdx.x & 255;
    int lane = threadIdx.x & 63;
    int wv = threadIdx.x >> 6;          // 0..3
    int l15 = lane & 15, q = lane >> 4, qb = q << 3;
    int rowb = rg << 4;

    __shared__ alignas(16) _Float16 sF[4096];   // exp(ed) for this head
    __shared__ alignas(16) _Float16 sG[4096];   // exp(0.2 ed)
    __shared__ float red[16][17];               // [row][o 0..15, den]
    __shared__ uint64_t lut[16];                // nibble -> two u32 half-masks

    {   // cooperative staging: 2 x 8 KB, coalesced float4
        const floatx4* Fg = (const floatx4*)(fh  + (h << 12));
        const floatx4* Gg = (const floatx4*)(f2h + (h << 12));
        floatx4* sFv = (floatx4*)sF;
        floatx4* sGv = (floatx4*)sG;
#pragma unroll
        for (int i = threadIdx.x; i < 512; i += 256) {
            sFv[i] = Fg[i];
            sGv[i] = Gg[i];
        }
    }
    for (int i = threadIdx.x; i < 16 * 17; i += 256) ((float*)red)[i] = 0.f;
    if (threadIdx.x < 16) {
        uint32_t v = threadIdx.x;
        uint32_t lo = ((v & 1) ? 0x0000FFFFu : 0u) | ((v & 2) ? 0xFFFF0000u : 0u);
        uint32_t hi = ((v & 4) ? 0x0000FFFFu : 0u) | ((v & 8) ? 0xFFFF0000u : 0u);
        lut[v] = ((uint64_t)hi << 32) | lo;
    }
    __syncthreads();

    int row = rowb + l15;
    float EnaF = en [(h << 12) + row];
    float EnbF = en2[(h << 12) + row];
    _Float16 ha = (_Float16)EnaF, hb = (_Float16)EnbF;
    half2t ena2 = {ha, ha}, enb2 = {hb, hb};
    int rowoff = row << 1;              // u32 index into bitsT column

    floatx4 acc, accd;
#pragma unroll
    for (int r = 0; r < 4; ++r) { acc[r] = 0.f; accd[r] = 0.f; }

    half8 ones;
#pragma unroll
    for (int j = 0; j < 8; ++j) ones[j] = (_Float16)1.0f;

    for (int step = 0; step < 32; ++step) {
        int m0 = (wv << 10) + (step << 5);
        union { half8 v; half2t h2[4]; uint32_t u[4]; } F, G, A;
        F.v = *(const half8*)(sF + m0 + qb);      // ds_read_b128, quad-broadcast
        G.v = *(const half8*)(sG + m0 + qb);
        half8 bfrag = *(const half8*)(Whf + ((size_t)((h << 7) + (m0 >> 5)) << 9) + (lane << 3));
        uint32_t w = bits[((m0 >> 6) << 13) + ((m0 >> 5) & 1) + rowoff] >> qb;
        uint64_t mlo = lut[w & 15];
        uint64_t mhi = lut[(w >> 4) & 15];
        uint32_t msk[4] = {(uint32_t)mlo, (uint32_t)(mlo >> 32),
                           (uint32_t)mhi, (uint32_t)(mhi >> 32)};
#pragma unroll
        for (int p = 0; p < 4; ++p) {
            half2t e = __builtin_elementwise_max(ena2 * F.h2[p], enb2 * G.h2[p]);
            A.u[p] = __builtin_bit_cast(uint32_t, e) & msk[p];
        }
        acc  = __builtin_amdgcn_mfma_f32_16x16x32_f16(A.v, bfrag, acc,  0, 0, 0);
        accd = __builtin_amdgcn_mfma_f32_16x16x32_f16(A.v, ones,  accd, 0, 0, 0);
    }

    // combine 4 wave partials via LDS atomics
#pragma unroll
    for (int r = 0; r < 4; ++r)
        atomicAdd(&red[(q << 2) + r][l15], acc[r]);
    if (l15 == 0) {
#pragma unroll
        for (int r = 0; r < 4; ++r)
            atomicAdd(&red[(q << 2) + r][16], accd[r]);
    }
    __syncthreads();

    {
        int r2 = threadIdx.x >> 4, c2 = threadIdx.x & 15;
        float v = red[r2][c2] / red[r2][16];
        v = v > 0.f ? v : expm1f(v);                     // jax.nn.elu
        x2[(size_t)(rowb + r2) * 128 + (h << 4) + c2] = v;
    }
}

// ---- kernel 4: Wh2 = x2 @ W_out (C=1), wave per row ----
__global__ __launch_bounds__(256) void k_wh2(const float* __restrict__ x2,
                                             const float* __restrict__ W_out,
                                             const float* __restrict__ a_out,
                                             float* __restrict__ Wh2,
                                             float* __restrict__ ed2) {
    int lane = threadIdx.x & 63;
    int n = (blockIdx.x << 2) + (threadIdx.x >> 6);
    const float2* xp = (const float2*)(x2 + (size_t)n * 128);
    const float2* wp = (const float2*)W_out;
    float2 xv = xp[lane], wv2 = wp[lane];
    float s = fmaf(xv.x, wv2.x, xv.y * wv2.y);
#pragma unroll
    for (int off = 32; off; off >>= 1) s += __shfl_xor(s, off);
    if (lane == 0) { Wh2[n] = s; ed2[n] = s * a_out[1]; }
}

// ---- kernel 5: layer-2 attention, block per row, 4 waves split m ----
__global__ __launch_bounds__(256) void k_attn2(const float* __restrict__ Wh2,
                                               const float* __restrict__ ed2,
                                               const float* __restrict__ a_out,
                                               const unsigned long long* __restrict__ bits,
                                               float* __restrict__ out) {
    int n = blockIdx.x;
    int lane = threadIdx.x & 63;
    int wv = threadIdx.x >> 6;
    float esn = Wh2[n] * a_out[0];
    float num = 0.f, den = 0.f;
#pragma unroll
    for (int it = 0; it < 16; ++it) {
        int w = (wv << 4) + it;
        int m = (w << 6) + lane;
        float w2 = Wh2[m];
        float s = esn + ed2[m];
        unsigned long long wb = bits[((size_t)w << 12) + n];
        s = fmaxf(s, 0.2f * s);
        float e = __expf(s);
        e = ((wb >> lane) & 1ull) ? e : 0.f;
        num = fmaf(e, w2, num);
        den += e;
    }
#pragma unroll
    for (int off = 32; off; off >>= 1) {
        num += __shfl_xor(num, off);
        den += __shfl_xor(den, off);
    }
    __shared__ float rn[4], rd[4];
    if (lane == 0) { rn[wv] = num; rd[wv] = den; }
    __syncthreads();
    if (threadIdx.x == 0) {
        float nn = rn[0] + rn[1] + rn[2] + rn[3];
        float dd = rd[0] + rd[1] + rd[2] + rd[3];
        float v = nn / dd;
        out[n] = v > 0.f ? v : expm1f(v);
    }
}

extern "C" void kernel_launch(void* const* d_in, const int* in_sizes, int n_in,
                              void* d_out, int out_size, void* d_ws, size_t ws_size,
                              hipStream_t stream) {
    const float* x     = (const float*)d_in[0];
    const int*   adj   = (const int*)d_in[1];
    const float* W     = (const float*)d_in[2];
    const float* a     = (const float*)d_in[3];
    const float* W_out = (const float*)d_in[4];
    const float* a_out = (const float*)d_in[5];
    float* out = (float*)d_out;

    char* ws = (char*)d_ws;
    _Float16* Whf = (_Float16*)(ws + OFF_WHF);
    float* en  = (float*)(ws + OFF_EN);
    float* en2 = (float*)(ws + OFF_EN2);
    _Float16* fhh  = (_Float16*)(ws + OFF_FH);
    _Float16* f2hh = (_Float16*)(ws + OFF_F2H);
    float* x2  = (float*)(ws + OFF_X2);
    float* Wh2 = (float*)(ws + OFF_WH2);
    float* ed2 = (float*)(ws + OFF_ED2);
    unsigned long long* bits = (unsigned long long*)(ws + OFF_BITS);

    hipLaunchKernelGGL(k_wh,    dim3(128),  dim3(256), 0, stream,
                       x, W, a, Whf, en, en2, fhh, f2hh);
    hipLaunchKernelGGL(k_bits,  dim3(4096), dim3(256), 0, stream, adj, bits);
    hipLaunchKernelGGL(k_attn1, dim3(2048), dim3(256), 0, stream,
                       Whf, en, en2, fhh, f2hh, (const uint32_t*)bits, x2);
    hipLaunchKernelGGL(k_wh2,   dim3(1024), dim3(256), 0, stream, x2, W_out, a_out, Wh2, ed2);
    hipLaunchKernelGGL(k_attn2, dim3(4096), dim3(256), 0, stream, Wh2, ed2, a_out, bits, out);
}

// Round 11
// 156.564 us; speedup vs baseline: 1.3684x; 1.0034x over previous
//
#include <hip/hip_runtime.h>
#include <stdint.h>

#define N 4096
#define NF 6
#define NO 16

typedef _Float16 half8 __attribute__((ext_vector_type(8)));
typedef _Float16 half2t __attribute__((ext_vector_type(2)));
typedef float floatx4 __attribute__((ext_vector_type(4)));

// ---------------- workspace layout (bytes) ----------------
#define OFF_WHF  0          // 8*4096*16 fp16 = 1 MB, B-fragment order [h][mtile][lane][j]
#define OFF_EN   1048576    // exp(es)      f32 [h][n]
#define OFF_EN2  1179648    // exp(0.2 es)  f32 [h][n]
#define OFF_FH   1310720    // exp(ed)      fp16 [h][n] 64 KB
#define OFF_F2H  1376256    // exp(0.2 ed)  fp16 [h][n] 64 KB
#define OFF_X2   1441792    // 4096*128 f32 = 2 MB
#define OFF_WH2  3538944    // 4096 f32
#define OFF_ED2  3555328    // 4096 f32
#define OFF_BITS 3571712    // TRANSPOSED bitmask u64 [64 words][4096 rows] = 2 MB

// ---- kernel 1: Wh = x@W per head -> fp16 B-frag; exp tables of es/ed ----
__global__ __launch_bounds__(256) void k_wh(const float* __restrict__ x,
                                            const float* __restrict__ W,
                                            const float* __restrict__ a,
                                            _Float16* __restrict__ Whf,
                                            float* __restrict__ en,
                                            float* __restrict__ en2,
                                            _Float16* __restrict__ fh,
                                            _Float16* __restrict__ f2h) {
    int tid = blockIdx.x * 256 + threadIdx.x;   // 32768 threads: (n,h)
    int n = tid >> 3, h = tid & 7;
    float xf[NF];
#pragma unroll
    for (int f = 0; f < NF; ++f) xf[f] = x[n * NF + f];
    float wh[NO];
#pragma unroll
    for (int o = 0; o < NO; ++o) {
        float s = 0.f;
#pragma unroll
        for (int f = 0; f < NF; ++f) s = fmaf(xf[f], W[(h * NF + f) * NO + o], s);
        wh[o] = s;
    }
    float s1 = 0.f, s2 = 0.f;
#pragma unroll
    for (int o = 0; o < NO; ++o) {
        s1 = fmaf(wh[o], a[h * 32 + o], s1);
        s2 = fmaf(wh[o], a[h * 32 + 16 + o], s2);
    }
    // B-fragment scatter: lane q*16+o of an m-tile holds B[k=q*8+j][o]
    int tile = n >> 5, q = (n >> 3) & 3, j = n & 7;
    _Float16* base = Whf + ((size_t)((h << 7) + tile) << 9) + j;
#pragma unroll
    for (int o = 0; o < NO; ++o) base[(size_t)(((q << 4) + o) << 3)] = (_Float16)wh[o];
    int idx = (h << 12) + n;
    en [idx] = __expf(s1);
    en2[idx] = __expf(0.2f * s1);
    fh [idx] = (_Float16)__expf(s2);
    f2h[idx] = (_Float16)__expf(0.2f * s2);
}

// ---- kernel 2: pack adjacency to TRANSPOSED bitmask [word][row] ----
__global__ __launch_bounds__(256) void k_bits(const int* __restrict__ adj,
                                              unsigned long long* __restrict__ bits) {
    int lane = threadIdx.x & 63;
    int wv = threadIdx.x >> 6;
    int n = blockIdx.x;
    int wbase = wv << 4;
    const int* row = adj + (size_t)n * N + (wbase << 6) + lane;
    int v[16];
#pragma unroll
    for (int i = 0; i < 16; ++i) v[i] = row[i << 6];
    unsigned long long b[16];
#pragma unroll
    for (int i = 0; i < 16; ++i) b[i] = __ballot(v[i] != 0);
    if (lane == 0) {
#pragma unroll
        for (int i = 0; i < 16; ++i)
            bits[((size_t)(wbase + i) << 12) + n] = b[i];
    }
}

// ---- kernel 3: layer-1 attention, packed-fp16 + MFMA, LDS tables, t=2 ----
// R10 removed L1 redundancy via LDS-staged F/F2. R11 amortizes the shared
// per-step costs (F/G ds_reads, bfrag global load, loop) over 2 row-tiles:
// 32 rows/block, 4 MFMAs/step. Whf L1 traffic halves (268->134 MB total),
// steps/SIMD halve. grid = 8 heads * 128 groups = 1024 blocks (4/CU,
// 16 waves/CU, LDS 18.4 KB); block = 4 waves; wave wv covers m in
// [wv*1024,...) in 32 steps of 32.
// e = max(exp(es)exp(ed), exp(.2es)exp(.2ed)); mask via AND with LDS LUT
// (fp16 +0.0 == 0x0000). A-frag A[n=lane&15][k=q*8+j]; C/D col=lane&15,
// row=q*4+reg.
__global__ __launch_bounds__(256, 4) void k_attn1(const _Float16* __restrict__ Whf,
                                                  const float* __restrict__ en,
                                                  const float* __restrict__ en2,
                                                  const _Float16* __restrict__ fh,
                                                  const _Float16* __restrict__ f2h,
                                                  const uint32_t* __restrict__ bits,
                                                  float* __restrict__ x2) {
    int h = blockIdx.x >> 7;
    int rg = blockIdx.x & 127;
    int lane = threadIdx.x & 63;
    int wv = threadIdx.x >> 6;          // 0..3
    int l15 = lane & 15, q = lane >> 4, qb = q << 3;
    int rowb = rg << 5;

    __shared__ alignas(16) _Float16 sF[4096];   // exp(ed) for this head
    __shared__ alignas(16) _Float16 sG[4096];   // exp(0.2 ed)
    __shared__ float red[32][17];               // [row][o 0..15, den]
    __shared__ uint64_t lut[16];                // nibble -> two u32 half-masks

    {   // cooperative staging: 2 x 8 KB, coalesced float4
        const floatx4* Fg = (const floatx4*)(fh  + (h << 12));
        const floatx4* Gg = (const floatx4*)(f2h + (h << 12));
        floatx4* sFv = (floatx4*)sF;
        floatx4* sGv = (floatx4*)sG;
#pragma unroll
        for (int i = threadIdx.x; i < 512; i += 256) {
            sFv[i] = Fg[i];
            sGv[i] = Gg[i];
        }
    }
    for (int i = threadIdx.x; i < 32 * 17; i += 256) ((float*)red)[i] = 0.f;
    if (threadIdx.x < 16) {
        uint32_t v = threadIdx.x;
        uint32_t lo = ((v & 1) ? 0x0000FFFFu : 0u) | ((v & 2) ? 0xFFFF0000u : 0u);
        uint32_t hi = ((v & 4) ? 0x0000FFFFu : 0u) | ((v & 8) ? 0xFFFF0000u : 0u);
        lut[v] = ((uint64_t)hi << 32) | lo;
    }
    __syncthreads();

    half2t ena2[2], enb2[2];
    int rowoff[2];
#pragma unroll
    for (int t = 0; t < 2; ++t) {
        int row = rowb + (t << 4) + l15;
        _Float16 ha = (_Float16)en [(h << 12) + row];
        _Float16 hb = (_Float16)en2[(h << 12) + row];
        ena2[t] = (half2t){ha, ha};
        enb2[t] = (half2t){hb, hb};
        rowoff[t] = row << 1;           // u32 index into bitsT column
    }

    floatx4 acc[2], accd[2];
#pragma unroll
    for (int t = 0; t < 2; ++t)
#pragma unroll
        for (int r = 0; r < 4; ++r) { acc[t][r] = 0.f; accd[t][r] = 0.f; }

    half8 ones;
#pragma unroll
    for (int j = 0; j < 8; ++j) ones[j] = (_Float16)1.0f;

    for (int step = 0; step < 32; ++step) {
        int m0 = (wv << 10) + (step << 5);
        union { half8 v; half2t h2[4]; uint32_t u[4]; } F, G;
        F.v = *(const half8*)(sF + m0 + qb);      // ds_read_b128, quad-broadcast
        G.v = *(const half8*)(sG + m0 + qb);
        half8 bfrag = *(const half8*)(Whf + ((size_t)((h << 7) + (m0 >> 5)) << 9) + (lane << 3));
        int wbase = ((m0 >> 6) << 13) + ((m0 >> 5) & 1);
#pragma unroll
        for (int t = 0; t < 2; ++t) {
            uint32_t w = bits[wbase + rowoff[t]] >> qb;
            uint64_t mlo = lut[w & 15];
            uint64_t mhi = lut[(w >> 4) & 15];
            uint32_t msk[4] = {(uint32_t)mlo, (uint32_t)(mlo >> 32),
                               (uint32_t)mhi, (uint32_t)(mhi >> 32)};
            union { half8 v; uint32_t u[4]; } A;
#pragma unroll
            for (int p = 0; p < 4; ++p) {
                half2t e = __builtin_elementwise_max(ena2[t] * F.h2[p], enb2[t] * G.h2[p]);
                A.u[p] = __builtin_bit_cast(uint32_t, e) & msk[p];
            }
            acc[t]  = __builtin_amdgcn_mfma_f32_16x16x32_f16(A.v, bfrag, acc[t],  0, 0, 0);
            accd[t] = __builtin_amdgcn_mfma_f32_16x16x32_f16(A.v, ones,  accd[t], 0, 0, 0);
        }
    }

    // combine 4 wave partials via LDS atomics
#pragma unroll
    for (int t = 0; t < 2; ++t) {
#pragma unroll
        for (int r = 0; r < 4; ++r)
            atomicAdd(&red[(t << 4) + (q << 2) + r][l15], acc[t][r]);
        if (l15 == 0) {
#pragma unroll
            for (int r = 0; r < 4; ++r)
                atomicAdd(&red[(t << 4) + (q << 2) + r][16], accd[t][r]);
        }
    }
    __syncthreads();

#pragma unroll
    for (int i = threadIdx.x; i < 512; i += 256) {
        int r2 = i >> 4, c2 = i & 15;
        float v = red[r2][c2] / red[r2][16];
        v = v > 0.f ? v : expm1f(v);                     // jax.nn.elu
        x2[(size_t)(rowb + r2) * 128 + (h << 4) + c2] = v;
    }
}

// ---- kernel 4: Wh2 = x2 @ W_out (C=1), wave per row ----
__global__ __launch_bounds__(256) void k_wh2(const float* __restrict__ x2,
                                             const float* __restrict__ W_out,
                                             const float* __restrict__ a_out,
                                             float* __restrict__ Wh2,
                                             float* __restrict__ ed2) {
    int lane = threadIdx.x & 63;
    int n = (blockIdx.x << 2) + (threadIdx.x >> 6);
    const float2* xp = (const float2*)(x2 + (size_t)n * 128);
    const float2* wp = (const float2*)W_out;
    float2 xv = xp[lane], wv2 = wp[lane];
    float s = fmaf(xv.x, wv2.x, xv.y * wv2.y);
#pragma unroll
    for (int off = 32; off; off >>= 1) s += __shfl_xor(s, off);
    if (lane == 0) { Wh2[n] = s; ed2[n] = s * a_out[1]; }
}

// ---- kernel 5: layer-2 attention, block per row, 4 waves split m ----
__global__ __launch_bounds__(256) void k_attn2(const float* __restrict__ Wh2,
                                               const float* __restrict__ ed2,
                                               const float* __restrict__ a_out,
                                               const unsigned long long* __restrict__ bits,
                                               float* __restrict__ out) {
    int n = blockIdx.x;
    int lane = threadIdx.x & 63;
    int wv = threadIdx.x >> 6;
    float esn = Wh2[n] * a_out[0];
    float num = 0.f, den = 0.f;
#pragma unroll
    for (int it = 0; it < 16; ++it) {
        int w = (wv << 4) + it;
        int m = (w << 6) + lane;
        float w2 = Wh2[m];
        float s = esn + ed2[m];
        unsigned long long wb = bits[((size_t)w << 12) + n];
        s = fmaxf(s, 0.2f * s);
        float e = __expf(s);
        e = ((wb >> lane) & 1ull) ? e : 0.f;
        num = fmaf(e, w2, num);
        den += e;
    }
#pragma unroll
    for (int off = 32; off; off >>= 1) {
        num += __shfl_xor(num, off);
        den += __shfl_xor(den, off);
    }
    __shared__ float rn[4], rd[4];
    if (lane == 0) { rn[wv] = num; rd[wv] = den; }
    __syncthreads();
    if (threadIdx.x == 0) {
        float nn = rn[0] + rn[1] + rn[2] + rn[3];
        float dd = rd[0] + rd[1] + rd[2] + rd[3];
        float v = nn / dd;
        out[n] = v > 0.f ? v : expm1f(v);
    }
}

extern "C" void kernel_launch(void* const* d_in, const int* in_sizes, int n_in,
                              void* d_out, int out_size, void* d_ws, size_t ws_size,
                              hipStream_t stream) {
    const float* x     = (const float*)d_in[0];
    const int*   adj   = (const int*)d_in[1];
    const float* W     = (const float*)d_in[2];
    const float* a     = (const float*)d_in[3];
    const float* W_out = (const float*)d_in[4];
    const float* a_out = (const float*)d_in[5];
    float* out = (float*)d_out;

    char* ws = (char*)d_ws;
    _Float16* Whf = (_Float16*)(ws + OFF_WHF);
    float* en  = (float*)(ws + OFF_EN);
    float* en2 = (float*)(ws + OFF_EN2);
    _Float16* fhh  = (_Float16*)(ws + OFF_FH);
    _Float16* f2hh = (_Float16*)(ws + OFF_F2H);
    float* x2  = (float*)(ws + OFF_X2);
    float* Wh2 = (float*)(ws + OFF_WH2);
    float* ed2 = (float*)(ws + OFF_ED2);
    unsigned long long* bits = (unsigned long long*)(ws + OFF_BITS);

    hipLaunchKernelGGL(k_wh,    dim3(128),  dim3(256), 0, stream,
                       x, W, a, Whf, en, en2, fhh, f2hh);
    hipLaunchKernelGGL(k_bits,  dim3(4096), dim3(256), 0, stream, adj, bits);
    hipLaunchKernelGGL(k_attn1, dim3(1024), dim3(256), 0, stream,
                       Whf, en, en2, fhh, f2hh, (const uint32_t*)bits, x2);
    hipLaunchKernelGGL(k_wh2,   dim3(1024), dim3(256), 0, stream, x2, W_out, a_out, Wh2, ed2);
    hipLaunchKernelGGL(k_attn2, dim3(4096), dim3(256), 0, stream, Wh2, ed2, a_out, bits, out);
}